// Round 3
// baseline (111.727 us; speedup 1.0000x reference)
//
#include <hip/hip_runtime.h>
#include <math.h>

#define Bq 8
#define Qq 256
#define Tt 128
#define Pp 100
#define Mm 512
#define Nn 1024  // B*T

// Block-wide sum over 256 threads (4 waves of 64). Result broadcast to all threads.
__device__ __forceinline__ float breduce256(float v, float* red) {
    #pragma unroll
    for (int off = 32; off > 0; off >>= 1) v += __shfl_down(v, off, 64);
    __syncthreads();                         // protect red[] reuse across calls
    if ((threadIdx.x & 63) == 0) red[threadIdx.x >> 6] = v;
    __syncthreads();
    return red[0] + red[1] + red[2] + red[3];
}

// One block per patch n = b*T + t. Computes per-patch squared chamfer.
__global__ __launch_bounds__(256) void geom_kernel(
    const float* __restrict__ pred_pts,   // [B,Q,P,3]
    const float* __restrict__ tgt_pts,    // [B,T,M,3]
    const int*   __restrict__ src_idx,    // [B,T]
    float*       __restrict__ per_patch)  // [N]
{
    __shared__ float s_tgt[Mm * 3];
    __shared__ float s_src[Pp * 3];
    __shared__ float red[4];
    const int n   = blockIdx.x;
    const int tid = threadIdx.x;
    const int b   = n >> 7;               // n / T
    const int q   = src_idx[n];
    const float* sp = pred_pts + (size_t)(b * Qq + q) * (Pp * 3);
    const float* tp = tgt_pts  + (size_t)n * (Mm * 3);
    for (int i = tid; i < Mm * 3; i += 256) s_tgt[i] = tp[i];
    for (int i = tid; i < Pp * 3; i += 256) s_src[i] = sp[i];
    __syncthreads();

    float contrib = 0.f;

    // Pass A: for each m, min over p.  Each thread owns m = tid and m = tid+256.
    {
        const float tx0 = s_tgt[tid*3+0], ty0 = s_tgt[tid*3+1], tz0 = s_tgt[tid*3+2];
        const float tx1 = s_tgt[(tid+256)*3+0], ty1 = s_tgt[(tid+256)*3+1], tz1 = s_tgt[(tid+256)*3+2];
        float mn0 = 3.4e38f, mn1 = 3.4e38f;
        #pragma unroll 4
        for (int p = 0; p < Pp; ++p) {
            const float sx = s_src[p*3+0], sy = s_src[p*3+1], sz = s_src[p*3+2]; // broadcast
            float dx = sx - tx0, dy = sy - ty0, dz = sz - tz0;
            const float d0 = fmaf(dx, dx, fmaf(dy, dy, dz * dz));
            dx = sx - tx1; dy = sy - ty1; dz = sz - tz1;
            const float d1 = fmaf(dx, dx, fmaf(dy, dy, dz * dz));
            mn0 = fminf(mn0, d0);
            mn1 = fminf(mn1, d1);
        }
        contrib = (mn0 + mn1) * (1.0f / Mm);   // partial of mean_m(min_p)
    }

    // Pass B: for each p, min over m.  Thread pair (2p, 2p+1) splits the m range.
    {
        const int p    = tid >> 1;
        const int half = tid & 1;
        float mn = 3.4e38f;
        if (p < Pp) {
            const float sx = s_src[p*3+0], sy = s_src[p*3+1], sz = s_src[p*3+2];
            const int m0 = half * 256;
            #pragma unroll 4
            for (int j = 0; j < 256; ++j) {
                const int m = m0 + j;
                const float dx = sx - s_tgt[m*3+0];
                const float dy = sy - s_tgt[m*3+1];
                const float dz = sz - s_tgt[m*3+2];
                mn = fminf(mn, fmaf(dx, dx, fmaf(dy, dy, dz * dz)));
            }
        }
        const float o = __shfl_xor(mn, 1, 64);
        mn = fminf(mn, o);
        if (p < Pp && half == 0) contrib += 0.2f * mn * (1.0f / Pp);
    }

    const float tot = breduce256(contrib, red);
    if (tid == 0) per_patch[n] = tot * (1.0f / 1.2f);
}

// Single block: CE loss, accuracies, cardinality, and final geometry sum.
__global__ __launch_bounds__(256) void cls_kernel(
    const float* __restrict__ logits,     // [B,Q,2]
    const int*   __restrict__ src_idx,    // [B,T]
    const float* __restrict__ per_patch,  // [N]
    float*       __restrict__ out)        // [5]
{
    __shared__ unsigned char matched[Bq * Qq];
    __shared__ int s_card[Bq];
    __shared__ float red[4];
    const int tid = threadIdx.x;
    for (int i = tid; i < Bq * Qq; i += 256) matched[i] = 0;
    if (tid < Bq) s_card[tid] = 0;
    __syncthreads();
    for (int i = tid; i < Nn; i += 256) {
        const int b = i >> 7;             // i / T
        matched[b * Qq + src_idx[i]] = 1;
    }
    __syncthreads();

    float sum_nll = 0.f, sum_wt = 0.f, cnt_overall = 0.f;
    #pragma unroll
    for (int k = 0; k < (Bq * Qq) / 256; ++k) {   // k == batch index b (Q==256)
        const int i = tid + k * 256;
        const float l0 = logits[2*i], l1 = logits[2*i + 1];
        const int   mt = matched[i];
        const float mx  = fmaxf(l0, l1);
        const float lse = mx + logf(expf(l0 - mx) + expf(l1 - mx));
        const float lt  = mt ? l0 : l1;           // logit of target class
        const float wt  = mt ? 1.0f : 0.1f;       // w[target], eos_coef = 0.1
        sum_nll += wt * (lse - lt);
        sum_wt  += wt;
        const int pred = (l0 >= l1) ? 0 : 1;      // argmax tie-break -> first
        const int c    = mt ? 0 : 1;
        cnt_overall += (pred == c) ? 1.f : 0.f;
        // cardinality: pred != last class  <=>  pred == 0
        const unsigned long long bal = __ballot(pred == 0);
        if ((tid & 63) == 0) atomicAdd(&s_card[k], (int)__popcll(bal));
    }

    float cnt_valid = 0.f;
    for (int i = tid; i < Nn; i += 256) {
        const int b = i >> 7;
        const int q = src_idx[i];
        const float l0 = logits[2*(b*Qq + q)], l1 = logits[2*(b*Qq + q) + 1];
        cnt_valid += (l0 >= l1) ? 1.f : 0.f;
    }

    float gsum = 0.f;
    for (int i = tid; i < Nn; i += 256) gsum += per_patch[i];

    const float t_nll = breduce256(sum_nll,     red);
    const float t_wt  = breduce256(sum_wt,      red);
    const float t_ov  = breduce256(cnt_overall, red);
    const float t_va  = breduce256(cnt_valid,   red);
    const float t_gs  = breduce256(gsum,        red);
    __syncthreads();

    if (tid == 0) {
        float cerr = 0.f;
        for (int b = 0; b < Bq; ++b) cerr += fabsf((float)s_card[b] - (float)Tt);
        out[0] = t_nll / t_wt;
        out[1] = 100.f * t_va / (float)Nn;
        out[2] = 100.f * t_ov / (float)(Bq * Qq);
        out[3] = cerr / (float)Bq;
        out[4] = t_gs / (float)Nn;
    }
}

extern "C" void kernel_launch(void* const* d_in, const int* in_sizes, int n_in,
                              void* d_out, int out_size, void* d_ws, size_t ws_size,
                              hipStream_t stream) {
    const float* logits   = (const float*)d_in[0];  // [B,Q,2]
    const float* pred_pts = (const float*)d_in[1];  // [B,Q,P,3]
    const float* tgt_pts  = (const float*)d_in[2];  // [B,T,M,3]
    const int*   src_idx  = (const int*)  d_in[3];  // [B,T]
    float* out       = (float*)d_out;               // 5 scalars
    float* per_patch = (float*)d_ws;                // 1024 floats scratch

    geom_kernel<<<Nn, 256, 0, stream>>>(pred_pts, tgt_pts, src_idx, per_patch);
    cls_kernel<<<1, 256, 0, stream>>>(logits, src_idx, per_patch, out);
}

// Round 4
// 111.052 us; speedup vs baseline: 1.0061x; 1.0061x over previous
//
#include <hip/hip_runtime.h>
#include <math.h>

#define Bq 8
#define Qq 256
#define Tt 128
#define Pp 100
#define Mm 512
#define Nn 1024  // B*T

// Block-wide sum over 256 threads (4 waves of 64). Result broadcast to all threads.
__device__ __forceinline__ float breduce256(float v, float* red) {
    #pragma unroll
    for (int off = 32; off > 0; off >>= 1) v += __shfl_down(v, off, 64);
    __syncthreads();                         // protect red[] reuse across calls
    if ((threadIdx.x & 63) == 0) red[threadIdx.x >> 6] = v;
    __syncthreads();
    return red[0] + red[1] + red[2] + red[3];
}

// One block per patch n = b*T + t. Computes per-patch squared chamfer.
// Points stored as padded float4 in LDS: inner-loop loads are single
// ds_read_b128, and both inner loops read WAVE-UNIFORM addresses (broadcast,
// bank-conflict-free).
__global__ __launch_bounds__(256) void geom_kernel(
    const float* __restrict__ pred_pts,   // [B,Q,P,3]
    const float* __restrict__ tgt_pts,    // [B,T,M,3]
    const int*   __restrict__ src_idx,    // [B,T]
    float*       __restrict__ per_patch)  // [N]
{
    __shared__ float4 s_tgt[Mm];          // 8 KB, xyz + pad
    __shared__ float4 s_src[Pp];          // 1.6 KB
    __shared__ float  s_bmin[128];        // pass-B cross-half combine
    __shared__ float  red[4];
    const int n   = blockIdx.x;
    const int tid = threadIdx.x;
    const int b   = n >> 7;               // n / T
    const int q   = src_idx[n];
    const float* sp = pred_pts + (size_t)(b * Qq + q) * (Pp * 3);
    const float* tp = tgt_pts  + (size_t)n * (Mm * 3);

    // Stage tgt: 512 pts × 3 floats = 768 float2; thread i repacks 2 points.
    {
        const float2* tp2 = (const float2*)tp;
        const float2 a = tp2[3*tid], c = tp2[3*tid+1], e = tp2[3*tid+2];
        s_tgt[2*tid]   = make_float4(a.x, a.y, c.x, 0.f);
        s_tgt[2*tid+1] = make_float4(c.y, e.x, e.y, 0.f);
    }
    // Stage src: 100 pts = 150 float2; threads 0..49 repack 2 points each.
    if (tid < 50) {
        const float2* sp2 = (const float2*)sp;
        const float2 a = sp2[3*tid], c = sp2[3*tid+1], e = sp2[3*tid+2];
        s_src[2*tid]   = make_float4(a.x, a.y, c.x, 0.f);
        s_src[2*tid+1] = make_float4(c.y, e.x, e.y, 0.f);
    }
    __syncthreads();

    float contrib = 0.f;

    // Pass A: for each m, min over p. Thread owns m = tid and m = tid+256.
    // s_src[p] is wave-uniform -> broadcast read.
    {
        const float4 t0 = s_tgt[tid];
        const float4 t1 = s_tgt[tid + 256];
        float mn0 = 3.4e38f, mn1 = 3.4e38f;
        #pragma unroll 4
        for (int p = 0; p < Pp; ++p) {
            const float4 s = s_src[p];
            float dx = s.x - t0.x, dy = s.y - t0.y, dz = s.z - t0.z;
            const float d0 = fmaf(dx, dx, fmaf(dy, dy, dz * dz));
            dx = s.x - t1.x; dy = s.y - t1.y; dz = s.z - t1.z;
            const float d1 = fmaf(dx, dx, fmaf(dy, dy, dz * dz));
            mn0 = fminf(mn0, d0);
            mn1 = fminf(mn1, d1);
        }
        contrib = (mn0 + mn1) * (1.0f / Mm);   // partial of mean_m(min_p)
    }

    // Pass B: for each p, min over m. half = tid>>7 is WAVE-UNIFORM, so
    // s_tgt[m0+j] is a broadcast read (single address per wave, no conflicts).
    {
        const int pr   = tid & 127;            // p index, active if < Pp
        const int half = tid >> 7;             // m-range half (wave-uniform)
        const int m0   = half * 256;
        float mn = 3.4e38f;
        if (pr < Pp) {
            const float4 s = s_src[pr];
            #pragma unroll 8
            for (int j = 0; j < 256; ++j) {
                const float4 t = s_tgt[m0 + j];
                const float dx = s.x - t.x;
                const float dy = s.y - t.y;
                const float dz = s.z - t.z;
                mn = fminf(mn, fmaf(dx, dx, fmaf(dy, dy, dz * dz)));
            }
        }
        // combine the two halves through LDS (partners are in different waves)
        if (half == 1 && pr < Pp) s_bmin[pr] = mn;
        __syncthreads();
        if (half == 0 && pr < Pp) {
            mn = fminf(mn, s_bmin[pr]);
            contrib += 0.2f * mn * (1.0f / Pp);
        }
    }

    const float tot = breduce256(contrib, red);
    if (tid == 0) per_patch[n] = tot * (1.0f / 1.2f);
}

// Single block: CE loss, accuracies, cardinality, and final geometry sum.
__global__ __launch_bounds__(256) void cls_kernel(
    const float* __restrict__ logits,     // [B,Q,2]
    const int*   __restrict__ src_idx,    // [B,T]
    const float* __restrict__ per_patch,  // [N]
    float*       __restrict__ out)        // [5]
{
    __shared__ unsigned char matched[Bq * Qq];
    __shared__ int s_card[Bq];
    __shared__ float red[4];
    const int tid = threadIdx.x;
    for (int i = tid; i < Bq * Qq; i += 256) matched[i] = 0;
    if (tid < Bq) s_card[tid] = 0;
    __syncthreads();
    for (int i = tid; i < Nn; i += 256) {
        const int b = i >> 7;             // i / T
        matched[b * Qq + src_idx[i]] = 1;
    }
    __syncthreads();

    float sum_nll = 0.f, sum_wt = 0.f, cnt_overall = 0.f;
    #pragma unroll
    for (int k = 0; k < (Bq * Qq) / 256; ++k) {   // k == batch index b (Q==256)
        const int i = tid + k * 256;
        const float l0 = logits[2*i], l1 = logits[2*i + 1];
        const int   mt = matched[i];
        const float mx  = fmaxf(l0, l1);
        const float lse = mx + logf(expf(l0 - mx) + expf(l1 - mx));
        const float lt  = mt ? l0 : l1;           // logit of target class
        const float wt  = mt ? 1.0f : 0.1f;       // w[target], eos_coef = 0.1
        sum_nll += wt * (lse - lt);
        sum_wt  += wt;
        const int pred = (l0 >= l1) ? 0 : 1;      // argmax tie-break -> first
        const int c    = mt ? 0 : 1;
        cnt_overall += (pred == c) ? 1.f : 0.f;
        // cardinality: pred != last class  <=>  pred == 0
        const unsigned long long bal = __ballot(pred == 0);
        if ((tid & 63) == 0) atomicAdd(&s_card[k], (int)__popcll(bal));
    }

    float cnt_valid = 0.f;
    for (int i = tid; i < Nn; i += 256) {
        const int b = i >> 7;
        const int q = src_idx[i];
        const float l0 = logits[2*(b*Qq + q)], l1 = logits[2*(b*Qq + q) + 1];
        cnt_valid += (l0 >= l1) ? 1.f : 0.f;
    }

    float gsum = 0.f;
    for (int i = tid; i < Nn; i += 256) gsum += per_patch[i];

    const float t_nll = breduce256(sum_nll,     red);
    const float t_wt  = breduce256(sum_wt,      red);
    const float t_ov  = breduce256(cnt_overall, red);
    const float t_va  = breduce256(cnt_valid,   red);
    const float t_gs  = breduce256(gsum,        red);
    __syncthreads();

    if (tid == 0) {
        float cerr = 0.f;
        for (int b = 0; b < Bq; ++b) cerr += fabsf((float)s_card[b] - (float)Tt);
        out[0] = t_nll / t_wt;
        out[1] = 100.f * t_va / (float)Nn;
        out[2] = 100.f * t_ov / (float)(Bq * Qq);
        out[3] = cerr / (float)Bq;
        out[4] = t_gs / (float)Nn;
    }
}

extern "C" void kernel_launch(void* const* d_in, const int* in_sizes, int n_in,
                              void* d_out, int out_size, void* d_ws, size_t ws_size,
                              hipStream_t stream) {
    const float* logits   = (const float*)d_in[0];  // [B,Q,2]
    const float* pred_pts = (const float*)d_in[1];  // [B,Q,P,3]
    const float* tgt_pts  = (const float*)d_in[2];  // [B,T,M,3]
    const int*   src_idx  = (const int*)  d_in[3];  // [B,T]
    float* out       = (float*)d_out;               // 5 scalars
    float* per_patch = (float*)d_ws;                // 1024 floats scratch

    geom_kernel<<<Nn, 256, 0, stream>>>(pred_pts, tgt_pts, src_idx, per_patch);
    cls_kernel<<<1, 256, 0, stream>>>(logits, src_idx, per_patch, out);
}

// Round 5
// 87.130 us; speedup vs baseline: 1.2823x; 1.2746x over previous
//
#include <hip/hip_runtime.h>
#include <math.h>

#define Bq 8
#define Qq 256
#define Tt 128
#define Pp 100
#define Mm 512
#define Nn 1024  // B*T

// Block-wide sum over 256 threads (4 waves of 64). Result broadcast to all threads.
__device__ __forceinline__ float breduce256(float v, float* red) {
    #pragma unroll
    for (int off = 32; off > 0; off >>= 1) v += __shfl_down(v, off, 64);
    __syncthreads();                         // protect red[] reuse across calls
    if ((threadIdx.x & 63) == 0) red[threadIdx.x >> 6] = v;
    __syncthreads();
    return red[0] + red[1] + red[2] + red[3];
}

// One block per patch. FUSED single-pass chamfer: each distance computed ONCE.
// Thread (c = tid>>5, g = tid&31) holds src points p = 4g..4g+3 in REGISTERS
// and sweeps tgt chunk m in [64c, 64c+64):
//   - per-p running min (pass B partial) stays in registers
//   - per-m min over p via ds atomicMin on uint-encoded nonneg floats (pass A)
// src is padded to 128 points with 5e18 sentinels: their d^2 ~ 7.5e37 never
// wins any min, so the hot loop has zero predication.
__global__ __launch_bounds__(256) void geom_kernel(
    const float* __restrict__ pred_pts,   // [B,Q,P,3]
    const float* __restrict__ tgt_pts,    // [B,T,M,3]
    const int*   __restrict__ src_idx,    // [B,T]
    float*       __restrict__ per_patch)  // [N]
{
    __shared__ float4   s_tgt[Mm];        // 8 KB
    __shared__ float4   s_src[128];       // 2 KB (padded)
    __shared__ unsigned s_amin[Mm];       // 2 KB: per-m min over p (as uint)
    __shared__ float    s_bpart[8][128];  // 4 KB: per-chunk per-p partial mins
    __shared__ float    red[4];
    const int n   = blockIdx.x;
    const int tid = threadIdx.x;
    const int b   = n >> 7;               // n / T
    const int q   = src_idx[n];
    const float* sp = pred_pts + (size_t)(b * Qq + q) * (Pp * 3);
    const float* tp = tgt_pts  + (size_t)n * (Mm * 3);

    // Stage tgt: 512 pts x 3 floats = 768 float2; thread repacks 2 points.
    {
        const float2* tp2 = (const float2*)tp;
        const float2 a = tp2[3*tid], c2 = tp2[3*tid+1], e = tp2[3*tid+2];
        s_tgt[2*tid]   = make_float4(a.x, a.y, c2.x, 0.f);
        s_tgt[2*tid+1] = make_float4(c2.y, e.x, e.y, 0.f);
    }
    // Stage src: threads 0..49 repack 2 points each; 100..127 write sentinels.
    if (tid < 50) {
        const float2* sp2 = (const float2*)sp;
        const float2 a = sp2[3*tid], c2 = sp2[3*tid+1], e = sp2[3*tid+2];
        s_src[2*tid]   = make_float4(a.x, a.y, c2.x, 0.f);
        s_src[2*tid+1] = make_float4(c2.y, e.x, e.y, 0.f);
    } else if (tid >= 100 && tid < 128) {
        s_src[tid] = make_float4(5e18f, 5e18f, 5e18f, 0.f);
    }
    // Init per-m min array (uint encoding of FLT_MAX).
    *(uint2*)&s_amin[2*tid] = make_uint2(0x7f7fffffu, 0x7f7fffffu);
    __syncthreads();

    const int g = tid & 31;
    const int c = tid >> 5;               // m-chunk 0..7
    const int mbase = c << 6;
    const float4 s0 = s_src[4*g+0], s1 = s_src[4*g+1],
                 s2 = s_src[4*g+2], s3 = s_src[4*g+3];
    float mn0 = 3.4e38f, mn1 = 3.4e38f, mn2 = 3.4e38f, mn3 = 3.4e38f;

    #pragma unroll 4
    for (int j = 0; j < 64; ++j) {
        const int m = mbase + ((j + g) & 63);   // rotate: distinct addr per lane
        const float4 t = s_tgt[m];
        float dx, dy, dz;
        dx = s0.x - t.x; dy = s0.y - t.y; dz = s0.z - t.z;
        const float d0 = fmaf(dx, dx, fmaf(dy, dy, dz * dz));
        dx = s1.x - t.x; dy = s1.y - t.y; dz = s1.z - t.z;
        const float d1 = fmaf(dx, dx, fmaf(dy, dy, dz * dz));
        dx = s2.x - t.x; dy = s2.y - t.y; dz = s2.z - t.z;
        const float d2 = fmaf(dx, dx, fmaf(dy, dy, dz * dz));
        dx = s3.x - t.x; dy = s3.y - t.y; dz = s3.z - t.z;
        const float d3 = fmaf(dx, dx, fmaf(dy, dy, dz * dz));
        mn0 = fminf(mn0, d0); mn1 = fminf(mn1, d1);
        mn2 = fminf(mn2, d2); mn3 = fminf(mn3, d3);
        const float pm = fminf(fminf(d0, d1), fminf(d2, d3));
        atomicMin(&s_amin[m], __float_as_uint(pm));   // nonneg: uint cmp == float cmp
    }

    // Per-p partials for this chunk -> LDS (contiguous 4 floats = one b128).
    *(float4*)&s_bpart[c][4*g] = make_float4(mn0, mn1, mn2, mn3);
    __syncthreads();

    float contrib;
    // Pass A: mean over m of min_p. Thread sums its 2 m-slots.
    {
        const uint2 u = *(const uint2*)&s_amin[2*tid];
        contrib = (__uint_as_float(u.x) + __uint_as_float(u.y)) * (1.0f / Mm);
    }
    // Pass B: combine the 8 chunk-partials; threads 0..99 own one p each.
    if (tid < Pp) {
        float mn = s_bpart[0][tid];
        #pragma unroll
        for (int cc = 1; cc < 8; ++cc) mn = fminf(mn, s_bpart[cc][tid]);
        contrib += 0.2f * mn * (1.0f / Pp);
    }

    const float tot = breduce256(contrib, red);
    if (tid == 0) per_patch[n] = tot * (1.0f / 1.2f);
}

// Single block: CE loss, accuracies, cardinality, and final geometry sum.
__global__ __launch_bounds__(256) void cls_kernel(
    const float* __restrict__ logits,     // [B,Q,2]
    const int*   __restrict__ src_idx,    // [B,T]
    const float* __restrict__ per_patch,  // [N]
    float*       __restrict__ out)        // [5]
{
    __shared__ unsigned char matched[Bq * Qq];
    __shared__ int s_card[Bq];
    __shared__ float red[4];
    const int tid = threadIdx.x;
    for (int i = tid; i < Bq * Qq; i += 256) matched[i] = 0;
    if (tid < Bq) s_card[tid] = 0;
    __syncthreads();
    for (int i = tid; i < Nn; i += 256) {
        const int b = i >> 7;             // i / T
        matched[b * Qq + src_idx[i]] = 1;
    }
    __syncthreads();

    float sum_nll = 0.f, sum_wt = 0.f, cnt_overall = 0.f;
    #pragma unroll
    for (int k = 0; k < (Bq * Qq) / 256; ++k) {   // k == batch index b (Q==256)
        const int i = tid + k * 256;
        const float l0 = logits[2*i], l1 = logits[2*i + 1];
        const int   mt = matched[i];
        const float mx  = fmaxf(l0, l1);
        const float lse = mx + logf(expf(l0 - mx) + expf(l1 - mx));
        const float lt  = mt ? l0 : l1;           // logit of target class
        const float wt  = mt ? 1.0f : 0.1f;       // w[target], eos_coef = 0.1
        sum_nll += wt * (lse - lt);
        sum_wt  += wt;
        const int pred = (l0 >= l1) ? 0 : 1;      // argmax tie-break -> first
        const int c    = mt ? 0 : 1;
        cnt_overall += (pred == c) ? 1.f : 0.f;
        // cardinality: pred != last class  <=>  pred == 0
        const unsigned long long bal = __ballot(pred == 0);
        if ((tid & 63) == 0) atomicAdd(&s_card[k], (int)__popcll(bal));
    }

    float cnt_valid = 0.f;
    for (int i = tid; i < Nn; i += 256) {
        const int b = i >> 7;
        const int q = src_idx[i];
        const float l0 = logits[2*(b*Qq + q)], l1 = logits[2*(b*Qq + q) + 1];
        cnt_valid += (l0 >= l1) ? 1.f : 0.f;
    }

    float gsum = 0.f;
    for (int i = tid; i < Nn; i += 256) gsum += per_patch[i];

    const float t_nll = breduce256(sum_nll,     red);
    const float t_wt  = breduce256(sum_wt,      red);
    const float t_ov  = breduce256(cnt_overall, red);
    const float t_va  = breduce256(cnt_valid,   red);
    const float t_gs  = breduce256(gsum,        red);
    __syncthreads();

    if (tid == 0) {
        float cerr = 0.f;
        for (int b = 0; b < Bq; ++b) cerr += fabsf((float)s_card[b] - (float)Tt);
        out[0] = t_nll / t_wt;
        out[1] = 100.f * t_va / (float)Nn;
        out[2] = 100.f * t_ov / (float)(Bq * Qq);
        out[3] = cerr / (float)Bq;
        out[4] = t_gs / (float)Nn;
    }
}

extern "C" void kernel_launch(void* const* d_in, const int* in_sizes, int n_in,
                              void* d_out, int out_size, void* d_ws, size_t ws_size,
                              hipStream_t stream) {
    const float* logits   = (const float*)d_in[0];  // [B,Q,2]
    const float* pred_pts = (const float*)d_in[1];  // [B,Q,P,3]
    const float* tgt_pts  = (const float*)d_in[2];  // [B,T,M,3]
    const int*   src_idx  = (const int*)  d_in[3];  // [B,T]
    float* out       = (float*)d_out;               // 5 scalars
    float* per_patch = (float*)d_ws;                // 1024 floats scratch

    geom_kernel<<<Nn, 256, 0, stream>>>(pred_pts, tgt_pts, src_idx, per_patch);
    cls_kernel<<<1, 256, 0, stream>>>(logits, src_idx, per_patch, out);
}